// Round 3
// baseline (5132.604 us; speedup 1.0000x reference)
//
#include <hip/hip_runtime.h>
#include <hip/hip_cooperative_groups.h>
#include <hip/hip_bf16.h>
#include <cmath>

namespace cg = cooperative_groups;

// ---- problem constants ----
constexpr int D     = 1024;
constexpr int HEADS = 16;
constexpr int DH    = 64;
constexpr int HID   = 4096;
constexpr int NL    = 12;
constexpr int NC    = 256;
constexpr int CSZ   = 128;
constexpr int AGE_V = 258;
constexpr int OBS   = 2048;
constexpr int OUTN  = 512;
constexpr int S     = 257;   // 1 + NC
constexpr int SP    = 288;   // padded rows: 3 * 96

typedef __attribute__((ext_vector_type(8))) short bf16x8v;
typedef __attribute__((ext_vector_type(4))) short short4v;
typedef __attribute__((ext_vector_type(4))) float f32x4;

__device__ __forceinline__ short bfc(float x) {
    __hip_bfloat16 h = __float2bfloat16(x);   // RNE
    return __builtin_bit_cast(short, h);
}
__device__ __forceinline__ void st_bf16x4(short* p, float4 v) {
    short4v s;
    s.x = bfc(v.x); s.y = bfc(v.y); s.z = bfc(v.z); s.w = bfc(v.w);
    *(short4v*)p = s;
}

// =====================================================================
// GEMM job: C[96x32 tile] = A[M,K](bf16) @ B[N,K](f32->bf16)^T
// 4 waves 2x2, per-wave 48x16 (3x1 mfma 16x16x32), register prefetch.
// EPI: 0 = f32 acc+bias, 1 = bf16 relu(acc+bias), 2 = atomicAdd f32
// =====================================================================
constexpr int BM = 96, BN = 32, BK = 64, LDT = 72;
constexpr int SMEM_BYTES = 21504;

template<int EPI>
__device__ __forceinline__ void gemm_job(char* smraw, const short* __restrict__ A,
                                         const float* __restrict__ Bm,
                                         const float* __restrict__ bias,
                                         void* __restrict__ Cp,
                                         int K, int N, int kbeg, int klen,
                                         int m0, int n0, int t) {
    short* As = (short*)smraw;              // 13824 B
    short* Bs = (short*)(smraw + 13824);    //  4608 B
    const int ar = t >> 3;            // 0..31
    const int ac = (t & 7) * 8;       // 0..56
    const short* Ab = A + (size_t)(m0 + ar) * K + kbeg + ac;
    const int sr = t >> 4;            // 0..15
    const int sc = (t & 15) * 4;      // 0..60
    const float* Bb = Bm + (size_t)(n0 + sr) * K + kbeg + sc;

    const int lane = t & 63, wave = t >> 6;
    const int wm = wave >> 1, wn = wave & 1;
    const int fr = lane & 15, quad = lane >> 4;
    const short* Abase = &As[(wm * 48 + fr) * LDT + quad * 8];
    const short* Bbase = &Bs[(wn * 16 + fr) * LDT + quad * 8];

    f32x4 acc[3] = {};
    bf16x8v areg[3];
    float4  breg[2];
    #pragma unroll
    for (int p = 0; p < 3; ++p)
        areg[p] = *(const bf16x8v*)(Ab + (size_t)(p * 32) * K);
    #pragma unroll
    for (int p = 0; p < 2; ++p)
        breg[p] = *(const float4*)(Bb + (size_t)(p * 16) * K);

    for (int k0 = 0; k0 < klen; k0 += BK) {
        __syncthreads();   // previous LDS consumers done
        #pragma unroll
        for (int p = 0; p < 3; ++p)
            *(bf16x8v*)&As[(p * 32 + ar) * LDT + ac] = areg[p];
        #pragma unroll
        for (int p = 0; p < 2; ++p)
            st_bf16x4(&Bs[(p * 16 + sr) * LDT + sc], breg[p]);
        __syncthreads();
        if (k0 + BK < klen) {   // prefetch next tile under MFMAs
            #pragma unroll
            for (int p = 0; p < 3; ++p)
                areg[p] = *(const bf16x8v*)(Ab + (size_t)(p * 32) * K + (k0 + BK));
            #pragma unroll
            for (int p = 0; p < 2; ++p)
                breg[p] = *(const float4*)(Bb + (size_t)(p * 16) * K + (k0 + BK));
        }
        #pragma unroll
        for (int kt = 0; kt < 2; ++kt) {
            bf16x8v af[3], bfv;
            #pragma unroll
            for (int mt = 0; mt < 3; ++mt)
                af[mt] = *(const bf16x8v*)(Abase + mt * 16 * LDT + kt * 32);
            bfv = *(const bf16x8v*)(Bbase + kt * 32);
            #pragma unroll
            for (int mt = 0; mt < 3; ++mt)
                acc[mt] = __builtin_amdgcn_mfma_f32_16x16x32_bf16(
                    af[mt], bfv, acc[mt], 0, 0, 0);
        }
    }

    #pragma unroll
    for (int mt = 0; mt < 3; ++mt) {
        const int m = m0 + wm * 48 + mt * 16 + quad * 4;
        const int n = n0 + wn * 16 + fr;
        if (EPI == 2) {
            float* C = (float*)Cp;
            #pragma unroll
            for (int r = 0; r < 4; ++r)
                atomicAdd(&C[(size_t)(m + r) * N + n], acc[mt][r]);
        } else if (EPI == 1) {
            short* C = (short*)Cp;
            const float bvv = bias[n];
            #pragma unroll
            for (int r = 0; r < 4; ++r)
                C[(size_t)(m + r) * N + n] = bfc(fmaxf(acc[mt][r] + bvv, 0.f));
        } else {
            float* C = (float*)Cp;
            const float bvv = bias[n];
            #pragma unroll
            for (int r = 0; r < 4; ++r)
                C[(size_t)(m + r) * N + n] = acc[mt][r] + bvv;
        }
    }
}

// =====================================================================
// attention job: 256 threads = 4 waves, wave = 1 query (4 queries/job).
// =====================================================================
constexpr int KT = 32, NT = 9;  // 9*32 = 288 >= 257

__device__ __forceinline__ void attn_job(char* smraw, const float* __restrict__ Q,
                                         const float* __restrict__ Km,
                                         const float* __restrict__ V,
                                         short* __restrict__ O,
                                         int h, int qt, int t) {
    float* Ks = (float*)smraw;                 // 32*66*4 = 8448
    float* Vs = (float*)(smraw + 8448);        // 32*64*4 = 8192
    float* pw = (float*)(smraw + 8448 + 8192); // 4*288*4 = 4608
    const int wq = t >> 6, lane = t & 63;
    const int q = qt * 4 + wq;
    const bool qok = q < S;
    const int k32 = lane & 31, dh2 = lane >> 5;

    float qr[32];
    #pragma unroll
    for (int i = 0; i < 32; ++i)
        qr[i] = qok ? Q[(size_t)q * D + h * DH + dh2 * 32 + i] : 0.f;

    float s[NT];
    for (int tile = 0; tile < NT; ++tile) {
        const int kk0 = tile * KT;
        __syncthreads();
        #pragma unroll
        for (int p = 0; p < 4; ++p) {
            const int idx = t + p * 256;
            const int kr = idx >> 5, c2 = (idx & 31) * 2;
            const int kg = kk0 + kr;
            float2 v = make_float2(0.f, 0.f);
            if (kg < S) v = *(const float2*)&Km[(size_t)kg * D + h * DH + c2];
            *(float2*)&Ks[kr * 66 + c2] = v;
        }
        __syncthreads();
        float dot = 0.f;
        const float* kp = &Ks[k32 * 66 + dh2 * 32];
        #pragma unroll
        for (int i = 0; i < 32; ++i) dot = fmaf(qr[i], kp[i], dot);
        dot += __shfl_xor(dot, 32, 64);
        s[tile] = (kk0 + k32 < S) ? dot * 0.125f : -1e30f;
    }
    float mx = -1e30f;
    #pragma unroll
    for (int j = 0; j < NT; ++j) mx = fmaxf(mx, s[j]);
    #pragma unroll
    for (int off = 32; off; off >>= 1) mx = fmaxf(mx, __shfl_xor(mx, off, 64));
    float sum = 0.f;
    #pragma unroll
    for (int j = 0; j < NT; ++j) {
        const float e = __expf(s[j] - mx);
        s[j] = e;
        sum += e;
    }
    #pragma unroll
    for (int off = 32; off; off >>= 1) sum += __shfl_xor(sum, off, 64);
    sum *= 0.5f;   // each key counted in both dh2 halves
    const float inv = 1.f / sum;
    if (qok && dh2 == 0) {
        #pragma unroll
        for (int j = 0; j < NT; ++j) pw[wq * 288 + j * KT + k32] = s[j] * inv;
    }
    float acc = 0.f;
    for (int tile = 0; tile < NT; ++tile) {
        const int kk0 = tile * KT;
        __syncthreads();
        #pragma unroll
        for (int p = 0; p < 2; ++p) {
            const int idx = t + p * 256;
            const int kr = idx >> 4, c4 = (idx & 15) * 4;
            const int kg = kk0 + kr;
            float4 v = make_float4(0.f, 0.f, 0.f, 0.f);
            if (kg < S) v = *(const float4*)&V[(size_t)kg * D + h * DH + c4];
            *(float4*)&Vs[kr * 64 + c4] = v;
        }
        __syncthreads();
        if (qok) {
            const float* pwp = &pw[wq * 288 + kk0];
            #pragma unroll
            for (int k = 0; k < KT; ++k)
                acc = fmaf(pwp[k], Vs[k * 64 + lane], acc);
        }
    }
    if (qok) O[(size_t)q * D + h * DH + lane] = bfc(acc);
}

// ---- embed observation job (one d) ----
__device__ __forceinline__ void embed_obs_job(char* smraw, const float* __restrict__ obs,
                                              const float* __restrict__ Wc,
                                              const float* __restrict__ bc,
                                              const float* __restrict__ bo0,
                                              float* __restrict__ H, short* __restrict__ HB,
                                              float* __restrict__ T, int d, int t) {
    float* red = (float*)smraw;
    const float4* w4 = (const float4*)&Wc[(size_t)d * OBS];
    const float4* o4 = (const float4*)obs;
    float acc = 0.f;
    #pragma unroll
    for (int i = t; i < OBS / 4; i += 256) {
        const float4 a = o4[i];
        const float4 b = w4[i];
        acc = fmaf(a.x, b.x, acc); acc = fmaf(a.y, b.y, acc);
        acc = fmaf(a.z, b.z, acc); acc = fmaf(a.w, b.w, acc);
    }
    __syncthreads();            // smem reuse guard across jobs
    red[t] = acc;
    __syncthreads();
    for (int off = 128; off; off >>= 1) {
        if (t < off) red[t] += red[t + off];
        __syncthreads();
    }
    if (t == 0) {
        const float v = red[0] + bc[d];
        H[d] = v;
        HB[d] = bfc(v);
        T[d] = v + bo0[d];
    }
}

// ---- embed concepts job: j -> (row, d-chunk); pads zeroed ----
__device__ __forceinline__ void embed_cpt_job(char* smraw, const float* __restrict__ concepts,
                                              const float* __restrict__ Wce,
                                              const float* __restrict__ bce,
                                              const float* __restrict__ Wa,
                                              const float* __restrict__ ba,
                                              const float* __restrict__ bo0,
                                              float* __restrict__ H, short* __restrict__ HB,
                                              short* __restrict__ ATT, float* __restrict__ T,
                                              int j, int t) {
    const int row = (j % 287) + 1;                 // 1..287
    const int d = (j / 287) * 256 + t;             // 0..1023
    if (row > NC) {                                // block-uniform branch
        H[(size_t)row * D + d] = 0.f;
        HB[(size_t)row * D + d] = 0;
        ATT[(size_t)row * D + d] = 0;
        T[(size_t)row * D + d] = bo0[d];
        return;
    }
    float* cs = (float*)smraw;
    const int i = row - 1;
    __syncthreads();            // smem reuse guard
    if (t < CSZ) cs[t] = concepts[(size_t)i * CSZ + t];
    __syncthreads();
    const float4* w4 = (const float4*)&Wce[(size_t)d * CSZ];
    const float4* c4 = (const float4*)cs;
    float acc = 0.f;
    #pragma unroll
    for (int c = 0; c < CSZ / 4; ++c) {
        const float4 a = c4[c];
        const float4 b = w4[c];
        acc = fmaf(a.x, b.x, acc); acc = fmaf(a.y, b.y, acc);
        acc = fmaf(a.z, b.z, acc); acc = fmaf(a.w, b.w, acc);
    }
    const float age = Wa[(size_t)d * AGE_V + i] +
                      ((float)i / 256.f) * Wa[(size_t)d * AGE_V + (AGE_V - 1)];
    const float v = acc + bce[d] + ba[d] + age;
    H[(size_t)row * D + d] = v;
    HB[(size_t)row * D + d] = bfc(v);
    T[(size_t)row * D + d] = v + bo0[d];
}

// ---- layernorm job (one row) ----
__device__ __forceinline__ void ln_job(char* smraw, const float* __restrict__ X,
                                       const float* __restrict__ g, const float* __restrict__ b,
                                       float* __restrict__ Y, short* __restrict__ Yb,
                                       float* __restrict__ Ti, const float* __restrict__ nbias,
                                       int r, int t) {
    float* r1 = (float*)smraw;
    float* r2 = r1 + 256;
    const float* x = X + (size_t)r * D;
    float sm = 0.f, ss = 0.f;
    float v[4];
    #pragma unroll
    for (int j = 0; j < 4; ++j) {
        const float u = x[t + j * 256];
        v[j] = u;
        sm += u;
        ss = fmaf(u, u, ss);
    }
    __syncthreads();            // smem reuse guard
    r1[t] = sm; r2[t] = ss;
    __syncthreads();
    for (int off = 128; off; off >>= 1) {
        if (t < off) { r1[t] += r1[t + off]; r2[t] += r2[t + off]; }
        __syncthreads();
    }
    const float m   = r1[0] * (1.f / D);
    const float var = r2[0] * (1.f / D) - m * m;
    const float rs  = rsqrtf(var + 1e-5f);
    #pragma unroll
    for (int j = 0; j < 4; ++j) {
        const int idx = t + j * 256;
        const float y = (v[j] - m) * rs * g[idx] + b[idx];
        Y[(size_t)r * D + idx] = y;
        Yb[(size_t)r * D + idx] = bfc(y);
        if (Ti) Ti[(size_t)r * D + idx] = y + nbias[idx];
    }
}

// ---- head job (one output element) ----
__device__ __forceinline__ void head_job(char* smraw, const float* __restrict__ H,
                                         const float* __restrict__ Wout,
                                         const float* __restrict__ bout,
                                         const float* __restrict__ Wcon,
                                         const float* __restrict__ bcon,
                                         float* __restrict__ out, int j, int t) {
    float* red = (float*)smraw;
    const float* w = (j < OUTN) ? &Wout[(size_t)j * D] : &Wcon[(size_t)(j - OUTN) * D];
    const float4* w4 = (const float4*)w;
    const float4* h4 = (const float4*)H;   // row 0
    const float4 a = h4[t];
    const float4 b = w4[t];
    float acc = a.x * b.x + a.y * b.y + a.z * b.z + a.w * b.w;
    __syncthreads();            // smem reuse guard
    red[t] = acc;
    __syncthreads();
    for (int off = 128; off; off >>= 1) {
        if (t < off) red[t] += red[t + off];
        __syncthreads();
    }
    if (t == 0) {
        const float v = red[0] + ((j < OUTN) ? bout[j] : bcon[j - OUTN]);
        out[j] = (j < OUTN) ? fmaxf(v, 0.f) : tanhf(v);
    }
}

// =====================================================================
// The cooperative mega-kernel: whole network, one launch, grid syncs.
// =====================================================================
struct MP {
    const float *obs, *concepts, *W_core, *b_core, *W_cemb, *b_cemb, *W_age, *b_age;
    const float *Wq, *bq, *Wk, *bk, *Wv, *bv, *Wo, *bo;
    const float *ln1g, *ln1b, *W1, *b1, *W2, *b2, *ln2g, *ln2b;
    const float *W_con, *b_con, *W_out, *b_out;
    float *outp;
    float *h, *tmpA, *tmpB, *qb, *kb, *vb;
    short *hb, *att, *mid;
};

__global__ __launch_bounds__(256, 2)
void mega(MP p) {
    __shared__ __align__(16) char smraw[SMEM_BYTES];
    cg::grid_group grid = cg::this_grid();
    const int t = threadIdx.x;
    const int nb = gridDim.x, bid = blockIdx.x;

    // ---- embed stage ----
    for (int j = bid; j < D; j += nb)
        embed_obs_job(smraw, p.obs, p.W_core, p.b_core, p.bo, p.h, p.hb, p.tmpA, j, t);
    for (int j = bid; j < 287 * 4; j += nb)
        embed_cpt_job(smraw, p.concepts, p.W_cemb, p.b_cemb, p.W_age, p.b_age, p.bo,
                      p.h, p.hb, p.att, p.tmpA, j, t);
    grid.sync();

    for (int l = 0; l < NL; ++l) {
        const size_t lo = (size_t)l * D * D;
        // qkv: 288 jobs
        for (int j = bid; j < 288; j += nb) {
            const int n = j & 31, m = (j >> 5) % 3, z = j / 96;
            const float *Bm, *bs;
            float* Cm;
            if (z == 0)      { Bm = p.Wq + lo; bs = p.bq + (size_t)l * D; Cm = p.qb; }
            else if (z == 1) { Bm = p.Wk + lo; bs = p.bk + (size_t)l * D; Cm = p.kb; }
            else             { Bm = p.Wv + lo; bs = p.bv + (size_t)l * D; Cm = p.vb; }
            gemm_job<0>(smraw, p.hb, Bm, bs, Cm, D, D, 0, D, m * 96, n * 32, t);
        }
        grid.sync();
        // attn: 65 q-tiles x 16 heads
        for (int j = bid; j < 65 * 16; j += nb)
            attn_job(smraw, p.qb, p.kb, p.vb, p.att, j / 65, j % 65, t);
        grid.sync();
        // O-proj split-4, atomic into tmpA (pre-initialized to h + bo[l])
        for (int j = bid; j < 384; j += nb) {
            const int n = j & 31, m = (j >> 5) % 3, z = j / 96;
            gemm_job<2>(smraw, p.att, p.Wo + lo, nullptr, p.tmpA, D, D,
                        z * 256, 256, m * 96, n * 32, t);
        }
        grid.sync();
        // ln1: h = LN(tmpA); tmpB = h + b2[l]
        for (int j = bid; j < S; j += nb)
            ln_job(smraw, p.tmpA, p.ln1g + (size_t)l * D, p.ln1b + (size_t)l * D,
                   p.h, p.hb, p.tmpB, p.b2 + (size_t)l * D, j, t);
        grid.sync();
        // W1 + relu -> bf16 mid
        for (int j = bid; j < 384; j += nb) {
            const int n = j % 128, m = j / 128;
            gemm_job<1>(smraw, p.hb, p.W1 + (size_t)l * HID * D, p.b1 + (size_t)l * HID,
                        p.mid, D, HID, 0, D, m * 96, n * 32, t);
        }
        grid.sync();
        // W2 split-4, atomic into tmpB
        for (int j = bid; j < 384; j += nb) {
            const int n = j & 31, m = (j >> 5) % 3, z = j / 96;
            gemm_job<2>(smraw, p.mid, p.W2 + (size_t)l * D * HID, nullptr, p.tmpB,
                        HID, D, z * 1024, 1024, m * 96, n * 32, t);
        }
        grid.sync();
        // ln2: h = LN(tmpB); tmpA = h + bo[l+1]
        float* ti = (l + 1 < NL) ? p.tmpA : nullptr;
        const float* nbias = (l + 1 < NL) ? p.bo + (size_t)(l + 1) * D : nullptr;
        for (int j = bid; j < S; j += nb)
            ln_job(smraw, p.tmpB, p.ln2g + (size_t)l * D, p.ln2b + (size_t)l * D,
                   p.h, p.hb, ti, nbias, j, t);
        grid.sync();
    }
    // head
    for (int j = bid; j < OUTN + CSZ; j += nb)
        head_job(smraw, p.h, p.W_out, p.b_out, p.W_con, p.b_con, p.outp, j, t);
}

// =====================================================================
// Fallback wrappers (round-2 multi-kernel path, same job bodies)
// =====================================================================
template<int EPI>
__global__ __launch_bounds__(256, 3)
void k_gemm(const short* __restrict__ A, const float* __restrict__ Bm,
            const float* __restrict__ bias, void* __restrict__ C,
            int K, int N, int klen) {
    __shared__ __align__(16) char sm[18432];
    gemm_job<EPI>(sm, A, Bm, bias, C, K, N, blockIdx.z * klen, klen,
                  blockIdx.y * BM, blockIdx.x * BN, threadIdx.x);
}
__global__ __launch_bounds__(256)
void k_attn(const float* Q, const float* Km, const float* V, short* O) {
    __shared__ __align__(16) char sm[21248];
    attn_job(sm, Q, Km, V, O, blockIdx.y, blockIdx.x, threadIdx.x);
}
__global__ __launch_bounds__(256)
void k_ln(const float* X, const float* g, const float* b, float* Y, short* Yb,
          float* Ti, const float* nb) {
    __shared__ __align__(16) char sm[2048];
    ln_job(sm, X, g, b, Y, Yb, Ti, nb, blockIdx.x, threadIdx.x);
}
__global__ __launch_bounds__(256)
void k_eobs(const float* obs, const float* Wc, const float* bc, const float* bo0,
            float* H, short* HB, float* T) {
    __shared__ __align__(16) char sm[1024];
    embed_obs_job(sm, obs, Wc, bc, bo0, H, HB, T, blockIdx.x, threadIdx.x);
}
__global__ __launch_bounds__(256)
void k_ecpt(const float* c, const float* Wce, const float* bce, const float* Wa,
            const float* ba, const float* bo0, float* H, short* HB, short* ATT, float* T) {
    __shared__ __align__(16) char sm[512];
    embed_cpt_job(sm, c, Wce, bce, Wa, ba, bo0, H, HB, ATT, T, blockIdx.x, threadIdx.x);
}
__global__ __launch_bounds__(256)
void k_head(const float* H, const float* Wout, const float* bout, const float* Wcon,
            const float* bcon, float* out) {
    __shared__ __align__(16) char sm[1024];
    head_job(sm, H, Wout, bout, Wcon, bcon, out, blockIdx.x, threadIdx.x);
}

extern "C" void kernel_launch(void* const* d_in, const int* in_sizes, int n_in,
                              void* d_out, int out_size, void* d_ws, size_t ws_size,
                              hipStream_t stream) {
    (void)in_sizes; (void)n_in; (void)out_size; (void)ws_size;
    const float* obs     = (const float*)d_in[0];
    const float* concepts= (const float*)d_in[1];
    const float* W_core  = (const float*)d_in[2];
    const float* b_core  = (const float*)d_in[3];
    const float* W_cemb  = (const float*)d_in[4];
    const float* b_cemb  = (const float*)d_in[5];
    const float* W_age   = (const float*)d_in[6];
    const float* b_age   = (const float*)d_in[7];
    const float* Wq      = (const float*)d_in[8];
    const float* bq      = (const float*)d_in[9];
    const float* Wk      = (const float*)d_in[10];
    const float* bk      = (const float*)d_in[11];
    const float* Wv      = (const float*)d_in[12];
    const float* bv      = (const float*)d_in[13];
    const float* Wo      = (const float*)d_in[14];
    const float* bo      = (const float*)d_in[15];
    const float* ln1g    = (const float*)d_in[16];
    const float* ln1b    = (const float*)d_in[17];
    const float* W1      = (const float*)d_in[18];
    const float* b1      = (const float*)d_in[19];
    const float* W2      = (const float*)d_in[20];
    const float* b2      = (const float*)d_in[21];
    const float* ln2g    = (const float*)d_in[22];
    const float* ln2b    = (const float*)d_in[23];
    const float* W_con   = (const float*)d_in[24];
    const float* b_con   = (const float*)d_in[25];
    const float* W_out   = (const float*)d_in[26];
    const float* b_out   = (const float*)d_in[27];
    float* outp = (float*)d_out;

    // workspace layout
    float* ws   = (float*)d_ws;
    float* h    = ws;                       // SP*D f32
    float* tmpA = h    + (size_t)SP * D;
    float* tmpB = tmpA + (size_t)SP * D;
    float* qb   = tmpB + (size_t)SP * D;
    float* kb   = qb   + (size_t)SP * D;
    float* vb   = kb   + (size_t)SP * D;
    short* hb   = (short*)(vb + (size_t)SP * D);  // SP*D bf16
    short* att  = hb  + (size_t)SP * D;           // SP*D bf16
    short* mid  = att + (size_t)SP * D;           // SP*HID bf16

    MP p;
    p.obs = obs; p.concepts = concepts; p.W_core = W_core; p.b_core = b_core;
    p.W_cemb = W_cemb; p.b_cemb = b_cemb; p.W_age = W_age; p.b_age = b_age;
    p.Wq = Wq; p.bq = bq; p.Wk = Wk; p.bk = bk; p.Wv = Wv; p.bv = bv;
    p.Wo = Wo; p.bo = bo; p.ln1g = ln1g; p.ln1b = ln1b; p.W1 = W1; p.b1 = b1;
    p.W2 = W2; p.b2 = b2; p.ln2g = ln2g; p.ln2b = ln2b;
    p.W_con = W_con; p.b_con = b_con; p.W_out = W_out; p.b_out = b_out;
    p.outp = outp;
    p.h = h; p.tmpA = tmpA; p.tmpB = tmpB; p.qb = qb; p.kb = kb; p.vb = vb;
    p.hb = hb; p.att = att; p.mid = mid;

    static int g_grid = 0;
    if (g_grid == 0) {
        int mb = 0;
        if (hipOccupancyMaxActiveBlocksPerMultiprocessor(&mb, mega, 256, 0) != hipSuccess
            || mb < 1) mb = 1;
        if (mb > 2) mb = 2;       // 512 blocks: sync cost vs round-count sweet spot
        g_grid = 256 * mb;
    }
    void* kp[1] = { (void*)&p };
    hipError_t e = hipLaunchCooperativeKernel(mega, dim3(g_grid), dim3(256), kp, 0u, stream);
    if (e != hipSuccess) {
        (void)hipGetLastError();  // clear; fall back to multi-kernel path
        k_eobs<<<dim3(D), 256, 0, stream>>>(obs, W_core, b_core, bo, h, hb, tmpA);
        k_ecpt<<<dim3(287 * 4), 256, 0, stream>>>(concepts, W_cemb, b_cemb, W_age,
                                                  b_age, bo, h, hb, att, tmpA);
        for (int l = 0; l < NL; ++l) {
            const size_t lo = (size_t)l * D * D;
            k_gemm<0><<<dim3(32, 3, 1), 256, 0, stream>>>(hb, Wq + lo, bq + (size_t)l * D, qb, D, D, D);
            k_gemm<0><<<dim3(32, 3, 1), 256, 0, stream>>>(hb, Wk + lo, bk + (size_t)l * D, kb, D, D, D);
            k_gemm<0><<<dim3(32, 3, 1), 256, 0, stream>>>(hb, Wv + lo, bv + (size_t)l * D, vb, D, D, D);
            k_attn<<<dim3(65, 16), 256, 0, stream>>>(qb, kb, vb, att);
            k_gemm<2><<<dim3(32, 3, 4), 256, 0, stream>>>(att, Wo + lo, nullptr, tmpA, D, D, 256);
            k_ln<<<dim3(S), 256, 0, stream>>>(tmpA, ln1g + (size_t)l * D, ln1b + (size_t)l * D,
                                              h, hb, tmpB, b2 + (size_t)l * D);
            k_gemm<1><<<dim3(128, 3, 1), 256, 0, stream>>>(hb, W1 + (size_t)l * HID * D,
                                                           b1 + (size_t)l * HID, mid, D, HID, D);
            k_gemm<2><<<dim3(32, 3, 8), 256, 0, stream>>>(mid, W2 + (size_t)l * D * HID,
                                                          nullptr, tmpB, HID, D, 512);
            float* ti = (l + 1 < NL) ? tmpA : nullptr;
            const float* nb2 = (l + 1 < NL) ? (bo + (size_t)(l + 1) * D) : nullptr;
            k_ln<<<dim3(S), 256, 0, stream>>>(tmpB, ln2g + (size_t)l * D, ln2b + (size_t)l * D,
                                              h, hb, ti, nb2);
        }
        k_head<<<dim3(OUTN + CSZ), 256, 0, stream>>>(h, W_out, b_out, W_con, b_con, outp);
    }
}

// Round 4
// 1957.202 us; speedup vs baseline: 2.6224x; 2.6224x over previous
//
#include <hip/hip_runtime.h>
#include <hip/hip_bf16.h>
#include <cmath>

// ---- problem constants ----
constexpr int D     = 1024;
constexpr int HEADS = 16;
constexpr int DH    = 64;
constexpr int HID   = 4096;
constexpr int NL    = 12;
constexpr int NC    = 256;
constexpr int CSZ   = 128;
constexpr int AGE_V = 258;
constexpr int OBS   = 2048;
constexpr int OUTN  = 512;
constexpr int S     = 257;   // 1 + NC
constexpr int SP    = 288;   // padded rows: 3 * 96

typedef __attribute__((ext_vector_type(8))) short bf16x8v;
typedef __attribute__((ext_vector_type(4))) short short4v;
typedef __attribute__((ext_vector_type(4))) float f32x4;

__device__ __forceinline__ short bfc(float x) {
    __hip_bfloat16 h = __float2bfloat16(x);   // RNE
    return __builtin_bit_cast(short, h);
}
__device__ __forceinline__ void st_bf16x4(short* p, float4 v) {
    short4v s;
    s.x = bfc(v.x); s.y = bfc(v.y); s.z = bfc(v.z); s.w = bfc(v.w);
    *(short4v*)p = s;
}

// =====================================================================
// MFMA GEMM, block tile 96x32, 4 waves 2x2, per-wave 48x16, BK=128.
// A modes:
//   LNA=false: A is pre-converted bf16, raw LDS copy.
//   LNA=true : A is fp32 activations; block computes per-row LN stats
//              (wave shfl reduce), applies LN during staging (then bf16
//              rounds, same logical point as a separate LN kernel).
//              Blocks (z==0, bx<4) also write the residual buffer
//              resd[row] = LN(x)[row] + resb  (fp32), 24 rows each.
// EPI: 0 = f32 acc+bias, 1 = bf16 relu(acc+bias), 2 = atomicAdd f32
// =====================================================================
constexpr int BM = 96, BN = 32, BK = 128, LDT = 136;  // +8 bf16 pad

template<int EPI, bool LNA>
__device__ __forceinline__ void gemm_core(const short* __restrict__ A,
                                          const float* __restrict__ Xf,
                                          const float* __restrict__ lng,
                                          const float* __restrict__ lnb,
                                          const float* __restrict__ resb,
                                          float* __restrict__ resd,
                                          int resid_sub,
                                          const float* __restrict__ Bm,
                                          const float* __restrict__ bias,
                                          void* __restrict__ Cp,
                                          int K, int N, int kbeg, int klen,
                                          int m0, int n0, int t) {
    __shared__ __align__(16) short As[BM * LDT];   // 26112 B
    __shared__ __align__(16) short Bs[BN * LDT];   //  8704 B
    __shared__ float s_mu[BM], s_ri[BM];
    const int lane = t & 63, wave = t >> 6;
    // A staging: 6 passes of 16 rows x 128 cols; thread = (ar, 8 cols)
    const int ar  = t >> 4;           // 0..15
    const int ac8 = (t & 15) * 8;     // 0..120
    const short* Ab = LNA ? nullptr : (A + (size_t)(m0 + ar) * K + kbeg + ac8);
    const float* Xa = LNA ? (Xf + (size_t)(m0 + ar) * K + kbeg + ac8) : nullptr;
    // B staging: 4 passes of 8 rows x 128 fp32 cols; thread = (sr, 4 cols)
    const int sr = t >> 5;            // 0..7
    const int sc = (t & 31) * 4;      // 0..124
    const float* Bb = Bm + (size_t)(n0 + sr) * K + kbeg + sc;

    const int wm = wave >> 1, wn = wave & 1;
    const int fr = lane & 15, quad = lane >> 4;
    const short* Abase = &As[(wm * 48 + fr) * LDT + quad * 8];
    const short* Bbase = &Bs[(wn * 16 + fr) * LDT + quad * 8];

    f32x4 acc[3] = {};
    bf16x8v araw[6];
    float4  aln[12];
    float4  breg[4];

    // ---- initial prefetch (issue early; hides under stats in LN mode) ----
    if constexpr (LNA) {
        #pragma unroll
        for (int p = 0; p < 6; ++p) {
            const float* src = Xa + (size_t)(p * 16) * K;
            aln[2 * p]     = *(const float4*)(src);
            aln[2 * p + 1] = *(const float4*)(src + 4);
        }
    } else {
        #pragma unroll
        for (int p = 0; p < 6; ++p)
            araw[p] = *(const bf16x8v*)(Ab + (size_t)(p * 16) * K);
    }
    #pragma unroll
    for (int p = 0; p < 4; ++p)
        breg[p] = *(const float4*)(Bb + (size_t)(p * 8) * K);

    if constexpr (LNA) {
        // ---- per-row LN stats: wave w handles rows w*24 .. w*24+23 ----
        #pragma unroll 2
        for (int i = 0; i < 24; ++i) {
            const int r = wave * 24 + i;
            const float4* xr = (const float4*)(Xf + (size_t)(m0 + r) * K);
            float sm = 0.f, ss = 0.f;
            #pragma unroll
            for (int j = 0; j < 4; ++j) {
                const float4 x = xr[lane * 4 + j];
                sm += x.x + x.y + x.z + x.w;
                ss = fmaf(x.x, x.x, fmaf(x.y, x.y, fmaf(x.z, x.z, fmaf(x.w, x.w, ss))));
            }
            #pragma unroll
            for (int off = 32; off; off >>= 1) {
                sm += __shfl_xor(sm, off, 64);
                ss += __shfl_xor(ss, off, 64);
            }
            if (lane == 0) {
                const float mu = sm * (1.f / 1024.f);
                s_mu[r] = mu;
                s_ri[r] = rsqrtf(ss * (1.f / 1024.f) - mu * mu + 1e-5f);
            }
        }
        __syncthreads();
        // ---- residual write: resd[row] = LN(x) + resb, rows sub*24..+24 ----
        if (resid_sub >= 0) {
            const int rbase = resid_sub * 24;
            #pragma unroll 4
            for (int i = 0; i < 24; ++i) {
                const int rl = rbase + i;
                const int c = t * 4;
                const float4 x  = *(const float4*)(Xf + (size_t)(m0 + rl) * K + c);
                const float4 g4 = *(const float4*)(lng + c);
                const float4 b4 = *(const float4*)(lnb + c);
                const float4 n4 = *(const float4*)(resb + c);
                const float mu = s_mu[rl], ri = s_ri[rl];
                float4 y;
                y.x = fmaf((x.x - mu) * ri, g4.x, b4.x) + n4.x;
                y.y = fmaf((x.y - mu) * ri, g4.y, b4.y) + n4.y;
                y.z = fmaf((x.z - mu) * ri, g4.z, b4.z) + n4.z;
                y.w = fmaf((x.w - mu) * ri, g4.w, b4.w) + n4.w;
                *(float4*)(resd + (size_t)(m0 + rl) * D + c) = y;
            }
        }
    }

    for (int k0 = 0; k0 < klen; k0 += BK) {
        __syncthreads();   // previous iter's LDS reads done
        if constexpr (LNA) {
            const float4 g0 = *(const float4*)(lng + kbeg + k0 + ac8);
            const float4 g1 = *(const float4*)(lng + kbeg + k0 + ac8 + 4);
            const float4 b0 = *(const float4*)(lnb + kbeg + k0 + ac8);
            const float4 b1 = *(const float4*)(lnb + kbeg + k0 + ac8 + 4);
            #pragma unroll
            for (int p = 0; p < 6; ++p) {
                const int r = p * 16 + ar;
                const float mu = s_mu[r], ri = s_ri[r];
                const float4 xa = aln[2 * p], xb = aln[2 * p + 1];
                bf16x8v o;
                o[0] = bfc(fmaf((xa.x - mu) * ri, g0.x, b0.x));
                o[1] = bfc(fmaf((xa.y - mu) * ri, g0.y, b0.y));
                o[2] = bfc(fmaf((xa.z - mu) * ri, g0.z, b0.z));
                o[3] = bfc(fmaf((xa.w - mu) * ri, g0.w, b0.w));
                o[4] = bfc(fmaf((xb.x - mu) * ri, g1.x, b1.x));
                o[5] = bfc(fmaf((xb.y - mu) * ri, g1.y, b1.y));
                o[6] = bfc(fmaf((xb.z - mu) * ri, g1.z, b1.z));
                o[7] = bfc(fmaf((xb.w - mu) * ri, g1.w, b1.w));
                *(bf16x8v*)&As[r * LDT + ac8] = o;
            }
        } else {
            #pragma unroll
            for (int p = 0; p < 6; ++p)
                *(bf16x8v*)&As[(p * 16 + ar) * LDT + ac8] = araw[p];
        }
        #pragma unroll
        for (int p = 0; p < 4; ++p)
            st_bf16x4(&Bs[(p * 8 + sr) * LDT + sc], breg[p]);
        __syncthreads();
        if (k0 + BK < klen) {   // prefetch next tile under this tile's MFMAs
            if constexpr (LNA) {
                #pragma unroll
                for (int p = 0; p < 6; ++p) {
                    const float* src = Xa + (size_t)(p * 16) * K + (k0 + BK);
                    aln[2 * p]     = *(const float4*)(src);
                    aln[2 * p + 1] = *(const float4*)(src + 4);
                }
            } else {
                #pragma unroll
                for (int p = 0; p < 6; ++p)
                    araw[p] = *(const bf16x8v*)(Ab + (size_t)(p * 16) * K + (k0 + BK));
            }
            #pragma unroll
            for (int p = 0; p < 4; ++p)
                breg[p] = *(const float4*)(Bb + (size_t)(p * 8) * K + (k0 + BK));
        }
        #pragma unroll
        for (int kt = 0; kt < 4; ++kt) {
            bf16x8v af[3], bfv;
            #pragma unroll
            for (int mt = 0; mt < 3; ++mt)
                af[mt] = *(const bf16x8v*)(Abase + mt * 16 * LDT + kt * 32);
            bfv = *(const bf16x8v*)(Bbase + kt * 32);
            #pragma unroll
            for (int mt = 0; mt < 3; ++mt)
                acc[mt] = __builtin_amdgcn_mfma_f32_16x16x32_bf16(
                    af[mt], bfv, acc[mt], 0, 0, 0);
        }
    }

    #pragma unroll
    for (int mt = 0; mt < 3; ++mt) {
        const int m = m0 + wm * 48 + mt * 16 + quad * 4;
        const int n = n0 + wn * 16 + fr;
        if (EPI == 2) {
            float* C = (float*)Cp;
            #pragma unroll
            for (int r = 0; r < 4; ++r)
                atomicAdd(&C[(size_t)(m + r) * N + n], acc[mt][r]);
        } else if (EPI == 1) {
            short* C = (short*)Cp;
            const float bvv = bias[n];
            #pragma unroll
            for (int r = 0; r < 4; ++r)
                C[(size_t)(m + r) * N + n] = bfc(fmaxf(acc[mt][r] + bvv, 0.f));
        } else {
            float* C = (float*)Cp;
            const float bvv = bias[n];
            #pragma unroll
            for (int r = 0; r < 4; ++r)
                C[(size_t)(m + r) * N + n] = acc[mt][r] + bvv;
        }
    }
}

struct QKVArgs {
    const float* B[3];
    const float* bias[3];
    float* C[3];
};

// raw-A split-K GEMM (O-proj, W2)
template<int EPI>
__global__ __launch_bounds__(256, 3)
void k_gemm(const short* __restrict__ A, const float* __restrict__ Bm,
            const float* __restrict__ bias, void* __restrict__ C,
            int K, int N, int klen) {
    gemm_core<EPI, false>(A, nullptr, nullptr, nullptr, nullptr, nullptr, -1,
                          Bm, bias, C, K, N, blockIdx.z * klen, klen,
                          blockIdx.y * BM, blockIdx.x * BN, threadIdx.x);
}

// raw-A QKV (layer 0)
__global__ __launch_bounds__(256, 3)
void k_gemm_qkv(const short* __restrict__ A, QKVArgs args) {
    const int z = blockIdx.z;
    gemm_core<0, false>(A, nullptr, nullptr, nullptr, nullptr, nullptr, -1,
                        args.B[z], args.bias[z], args.C[z], D, D, 0, D,
                        blockIdx.y * BM, blockIdx.x * BN, threadIdx.x);
}

// LN-fused QKV (layers >= 1): A = LN(X) with prev-layer ln2 params;
// (z==0, bx<4) blocks also write tmpA = LN(X) + bo[l]
__global__ __launch_bounds__(256, 2)
void k_gemm_qkv_ln(const float* __restrict__ X, const float* __restrict__ lng,
                   const float* __restrict__ lnb, const float* __restrict__ resb,
                   float* __restrict__ resd, QKVArgs args) {
    const int z = blockIdx.z;
    const int rsub = (z == 0 && blockIdx.x < 4) ? (int)blockIdx.x : -1;
    gemm_core<0, true>(nullptr, X, lng, lnb, resb, resd, rsub,
                       args.B[z], args.bias[z], args.C[z], D, D, 0, D,
                       blockIdx.y * BM, blockIdx.x * BN, threadIdx.x);
}

// LN-fused W1 (+relu, bf16 out): A = LN(tmpA) with ln1 params;
// bx<4 blocks also write tmpB = LN(tmpA) + b2[l]
__global__ __launch_bounds__(256, 2)
void k_gemm_w1_ln(const float* __restrict__ X, const float* __restrict__ lng,
                  const float* __restrict__ lnb, const float* __restrict__ resb,
                  float* __restrict__ resd, const float* __restrict__ Bm,
                  const float* __restrict__ bias, short* __restrict__ C) {
    const int rsub = (blockIdx.x < 4) ? (int)blockIdx.x : -1;
    gemm_core<1, true>(nullptr, X, lng, lnb, resb, resd, rsub,
                       Bm, bias, C, D, HID, 0, D,
                       blockIdx.y * BM, blockIdx.x * BN, threadIdx.x);
}

// =====================================================================
// attention: block = (8 queries, head). 512 threads = 8 waves.
// =====================================================================
constexpr int QB = 8, KT = 32, NT = 9;  // 9*32 = 288 >= 257

__global__ __launch_bounds__(512)
void k_attn(const float* __restrict__ Q, const float* __restrict__ Km,
            const float* __restrict__ V, short* __restrict__ O) {
    __shared__ float Ks[KT * 66];
    __shared__ float Vs[KT * 64];
    __shared__ float pw[QB][NT * KT];
    const int h = blockIdx.y;
    const int t = threadIdx.x;
    const int wq = t >> 6, lane = t & 63;
    const int q = blockIdx.x * QB + wq;
    const bool qok = q < S;
    const int k32 = lane & 31, dh2 = lane >> 5;

    float qr[32];
    #pragma unroll
    for (int i = 0; i < 32; ++i)
        qr[i] = qok ? Q[(size_t)q * D + h * DH + dh2 * 32 + i] : 0.f;

    float s[NT];
    for (int tile = 0; tile < NT; ++tile) {
        const int kk0 = tile * KT;
        __syncthreads();
        #pragma unroll
        for (int p = 0; p < 2; ++p) {
            const int idx = t + p * 512;
            const int kr = idx >> 5, c2 = (idx & 31) * 2;
            const int kg = kk0 + kr;
            float2 v = make_float2(0.f, 0.f);
            if (kg < S) v = *(const float2*)&Km[(size_t)kg * D + h * DH + c2];
            *(float2*)&Ks[kr * 66 + c2] = v;
        }
        __syncthreads();
        float dot = 0.f;
        const float* kp = &Ks[k32 * 66 + dh2 * 32];
        #pragma unroll
        for (int i = 0; i < 32; ++i) dot = fmaf(qr[i], kp[i], dot);
        dot += __shfl_xor(dot, 32, 64);
        s[tile] = (kk0 + k32 < S) ? dot * 0.125f : -1e30f;
    }
    float mx = -1e30f;
    #pragma unroll
    for (int j = 0; j < NT; ++j) mx = fmaxf(mx, s[j]);
    #pragma unroll
    for (int off = 32; off; off >>= 1) mx = fmaxf(mx, __shfl_xor(mx, off, 64));
    float sum = 0.f;
    #pragma unroll
    for (int j = 0; j < NT; ++j) {
        const float e = __expf(s[j] - mx);
        s[j] = e;
        sum += e;
    }
    #pragma unroll
    for (int off = 32; off; off >>= 1) sum += __shfl_xor(sum, off, 64);
    sum *= 0.5f;   // each key counted in both dh2 halves
    const float inv = 1.f / sum;
    if (qok && dh2 == 0) {
        #pragma unroll
        for (int j = 0; j < NT; ++j) pw[wq][j * KT + k32] = s[j] * inv;
    }
    float acc = 0.f;
    for (int tile = 0; tile < NT; ++tile) {
        const int kk0 = tile * KT;
        __syncthreads();
        {
            const int kr = t >> 4, c4 = (t & 15) * 4;
            const int kg = kk0 + kr;
            float4 v = make_float4(0.f, 0.f, 0.f, 0.f);
            if (kg < S) v = *(const float4*)&V[(size_t)kg * D + h * DH + c4];
            *(float4*)&Vs[kr * 64 + c4] = v;
        }
        __syncthreads();
        if (qok) {
            const float* pwp = &pw[wq][kk0];
            #pragma unroll
            for (int k = 0; k < KT; ++k)
                acc = fmaf(pwp[k], Vs[k * 64 + lane], acc);
        }
    }
    if (qok) O[(size_t)q * D + h * DH + lane] = bfc(acc);
}

// ---- merged embed: blocks [0,D) = obs dims, [D, D+1148) = concept rows ----
__global__ __launch_bounds__(256)
void k_embed(const float* __restrict__ obs, const float* __restrict__ Wc,
             const float* __restrict__ bc,
             const float* __restrict__ concepts, const float* __restrict__ Wce,
             const float* __restrict__ bce, const float* __restrict__ Wa,
             const float* __restrict__ ba, const float* __restrict__ bo0,
             short* __restrict__ HB, short* __restrict__ ATT,
             float* __restrict__ T) {
    const int t = threadIdx.x;
    __shared__ float red[256];
    if (blockIdx.x < D) {
        const int d = blockIdx.x;
        const float4* w4 = (const float4*)&Wc[(size_t)d * OBS];
        const float4* o4 = (const float4*)obs;
        float acc = 0.f;
        #pragma unroll
        for (int i = t; i < OBS / 4; i += 256) {
            const float4 a = o4[i];
            const float4 b = w4[i];
            acc = fmaf(a.x, b.x, acc); acc = fmaf(a.y, b.y, acc);
            acc = fmaf(a.z, b.z, acc); acc = fmaf(a.w, b.w, acc);
        }
        red[t] = acc;
        __syncthreads();
        for (int off = 128; off; off >>= 1) {
            if (t < off) red[t] += red[t + off];
            __syncthreads();
        }
        if (t == 0) {
            const float v = red[0] + bc[d];
            HB[d] = bfc(v);
            T[d] = v + bo0[d];
        }
        return;
    }
    const int j = blockIdx.x - D;                  // 0..1147
    const int row = (j % 287) + 1;                 // 1..287
    const int d = (j / 287) * 256 + t;             // 0..1023
    if (row > NC) {
        HB[(size_t)row * D + d] = 0;
        ATT[(size_t)row * D + d] = 0;
        T[(size_t)row * D + d] = bo0[d];
        return;
    }
    const int i = row - 1;
    if (t < CSZ) red[t] = concepts[(size_t)i * CSZ + t];
    __syncthreads();
    const float4* w4 = (const float4*)&Wce[(size_t)d * CSZ];
    const float4* c4 = (const float4*)red;
    float acc = 0.f;
    #pragma unroll
    for (int c = 0; c < CSZ / 4; ++c) {
        const float4 a = c4[c];
        const float4 b = w4[c];
        acc = fmaf(a.x, b.x, acc); acc = fmaf(a.y, b.y, acc);
        acc = fmaf(a.z, b.z, acc); acc = fmaf(a.w, b.w, acc);
    }
    const float age = Wa[(size_t)d * AGE_V + i] +
                      ((float)i / 256.f) * Wa[(size_t)d * AGE_V + (AGE_V - 1)];
    const float v = acc + bce[d] + ba[d] + age;
    HB[(size_t)row * D + d] = bfc(v);
    T[(size_t)row * D + d] = v + bo0[d];
}

// ---- head with fused final ln2 (row 0 only) ----
__global__ __launch_bounds__(256)
void k_head_ln(const float* __restrict__ X, const float* __restrict__ g,
               const float* __restrict__ b, const float* __restrict__ Wout,
               const float* __restrict__ bout, const float* __restrict__ Wcon,
               const float* __restrict__ bcon, float* __restrict__ out) {
    const int j = blockIdx.x;   // 0..639
    const int t = threadIdx.x;
    __shared__ float r1[256], r2[256];
    const float4 x = ((const float4*)X)[t];   // row 0
    float sm = x.x + x.y + x.z + x.w;
    float ss = fmaf(x.x, x.x, fmaf(x.y, x.y, fmaf(x.z, x.z, x.w * x.w)));
    r1[t] = sm; r2[t] = ss;
    __syncthreads();
    for (int off = 128; off; off >>= 1) {
        if (t < off) { r1[t] += r1[t + off]; r2[t] += r2[t + off]; }
        __syncthreads();
    }
    const float mu  = r1[0] * (1.f / D);
    const float var = r2[0] * (1.f / D) - mu * mu;
    const float ri  = rsqrtf(var + 1e-5f);
    const float4 g4 = ((const float4*)g)[t];
    const float4 b4 = ((const float4*)b)[t];
    float4 y;
    y.x = (x.x - mu) * ri * g4.x + b4.x;
    y.y = (x.y - mu) * ri * g4.y + b4.y;
    y.z = (x.z - mu) * ri * g4.z + b4.z;
    y.w = (x.w - mu) * ri * g4.w + b4.w;
    const float* w = (j < OUTN) ? &Wout[(size_t)j * D] : &Wcon[(size_t)(j - OUTN) * D];
    const float4 w4 = ((const float4*)w)[t];
    float acc = y.x * w4.x + y.y * w4.y + y.z * w4.z + y.w * w4.w;
    __syncthreads();
    r1[t] = acc;
    __syncthreads();
    for (int off = 128; off; off >>= 1) {
        if (t < off) r1[t] += r1[t + off];
        __syncthreads();
    }
    if (t == 0) {
        const float v = r1[0] + ((j < OUTN) ? bout[j] : bcon[j - OUTN]);
        out[j] = (j < OUTN) ? fmaxf(v, 0.f) : tanhf(v);
    }
}

extern "C" void kernel_launch(void* const* d_in, const int* in_sizes, int n_in,
                              void* d_out, int out_size, void* d_ws, size_t ws_size,
                              hipStream_t stream) {
    (void)in_sizes; (void)n_in; (void)out_size; (void)ws_size;
    const float* obs     = (const float*)d_in[0];
    const float* concepts= (const float*)d_in[1];
    const float* W_core  = (const float*)d_in[2];
    const float* b_core  = (const float*)d_in[3];
    const float* W_cemb  = (const float*)d_in[4];
    const float* b_cemb  = (const float*)d_in[5];
    const float* W_age   = (const float*)d_in[6];
    const float* b_age   = (const float*)d_in[7];
    const float* Wq      = (const float*)d_in[8];
    const float* bq      = (const float*)d_in[9];
    const float* Wk      = (const float*)d_in[10];
    const float* bk      = (const float*)d_in[11];
    const float* Wv      = (const float*)d_in[12];
    const float* bv      = (const float*)d_in[13];
    const float* Wo      = (const float*)d_in[14];
    const float* bo      = (const float*)d_in[15];
    const float* ln1g    = (const float*)d_in[16];
    const float* ln1b    = (const float*)d_in[17];
    const float* W1      = (const float*)d_in[18];
    const float* b1      = (const float*)d_in[19];
    const float* W2      = (const float*)d_in[20];
    const float* b2      = (const float*)d_in[21];
    const float* ln2g    = (const float*)d_in[22];
    const float* ln2b    = (const float*)d_in[23];
    const float* W_con   = (const float*)d_in[24];
    const float* b_con   = (const float*)d_in[25];
    const float* W_out   = (const float*)d_in[26];
    const float* b_out   = (const float*)d_in[27];
    float* outp = (float*)d_out;

    // workspace layout
    float* ws   = (float*)d_ws;
    float* tmpA = ws;                       // SP*D f32 (O-proj accumulator)
    float* tmpB = tmpA + (size_t)SP * D;    // SP*D f32 (FFN accumulator)
    float* qb   = tmpB + (size_t)SP * D;    // SP*D f32
    float* kb   = qb   + (size_t)SP * D;    // SP*D f32
    float* vb   = kb   + (size_t)SP * D;    // SP*D f32
    short* hb   = (short*)(vb + (size_t)SP * D);  // SP*D bf16 (embed out)
    short* att  = hb  + (size_t)SP * D;           // SP*D bf16
    short* mid  = att + (size_t)SP * D;           // SP*HID bf16

    // embed: hb (bf16), att pad rows zeroed, tmpA = x + bo[0]
    k_embed<<<dim3(D + 287 * 4), 256, 0, stream>>>(
        obs, W_core, b_core, concepts, W_cemb, b_cemb, W_age, b_age, bo,
        hb, att, tmpA);

    for (int l = 0; l < NL; ++l) {
        const size_t lo = (size_t)l * D * D;
        QKVArgs qa;
        qa.B[0] = Wq + lo;  qa.bias[0] = bq + (size_t)l * D;  qa.C[0] = qb;
        qa.B[1] = Wk + lo;  qa.bias[1] = bk + (size_t)l * D;  qa.C[1] = kb;
        qa.B[2] = Wv + lo;  qa.bias[2] = bv + (size_t)l * D;  qa.C[2] = vb;
        if (l == 0) {
            k_gemm_qkv<<<dim3(32, 3, 3), 256, 0, stream>>>(hb, qa);
        } else {
            // A = LN2_{l-1}(tmpB); also writes tmpA = LN2(tmpB) + bo[l]
            k_gemm_qkv_ln<<<dim3(32, 3, 3), 256, 0, stream>>>(
                tmpB, ln2g + (size_t)(l - 1) * D, ln2b + (size_t)(l - 1) * D,
                bo + (size_t)l * D, tmpA, qa);
        }
        k_attn<<<dim3((S + QB - 1) / QB, HEADS), 512, 0, stream>>>(qb, kb, vb, att);
        // O-proj: atomic into tmpA, split-K x4
        k_gemm<2><<<dim3(32, 3, 4), 256, 0, stream>>>(
            att, Wo + lo, nullptr, tmpA, D, D, 256);
        // W1: A = LN1(tmpA), +relu -> bf16 mid; also writes tmpB = LN1(tmpA)+b2
        k_gemm_w1_ln<<<dim3(128, 3), 256, 0, stream>>>(
            tmpA, ln1g + (size_t)l * D, ln1b + (size_t)l * D,
            b2 + (size_t)l * D, tmpB,
            W1 + (size_t)l * HID * D, b1 + (size_t)l * HID, mid);
        // W2: atomic into tmpB, split-K x8
        k_gemm<2><<<dim3(32, 3, 8), 256, 0, stream>>>(
            mid, W2 + (size_t)l * D * HID, nullptr, tmpB, HID, D, 512);
    }
    // head with fused final LN2 (row 0)
    k_head_ln<<<dim3(OUTN + CSZ), 256, 0, stream>>>(
        tmpB, ln2g + (size_t)(NL - 1) * D, ln2b + (size_t)(NL - 1) * D,
        W_out, b_out, W_con, b_con, outp);
}